// Round 1
// baseline (692.734 us; speedup 1.0000x reference)
//
#include <hip/hip_runtime.h>
#include <hip/hip_bf16.h>
#include <math.h>

typedef __bf16 bf16x8 __attribute__((ext_vector_type(8)));
typedef short  s16x8  __attribute__((ext_vector_type(8)));
typedef float  f32x4  __attribute__((ext_vector_type(4)));
typedef unsigned short u16;

// ---- sizes ----
#define NN 32
#define CC 256
#define HH 56
#define WW 56
#define HP 68            // padded spatial (6 halo each side)
#define XP2_BYTES 75759616ull            // 32*68*68*256*2
#define XP2_OFF 0ull
#define WT3_OFF 75759616ull              // 25*8*256*32*2 = 3276800
#define T1_OFF  79036416ull              // 32*256*56*4 = 1835008
#define T9_OFF  80871424ull              // 32*56*56*4

__device__ inline u16 f2bf(float f) {
    unsigned int u = __builtin_bit_cast(unsigned int, f);
    u = (u + 0x7fffu + ((u >> 16) & 1u)) >> 16;   // RNE
    return (u16)u;
}

__device__ inline void gl_lds16(const char* g, char* l) {
    __builtin_amdgcn_global_load_lds(
        (const __attribute__((address_space(1))) unsigned int*)g,
        (__attribute__((address_space(3))) unsigned int*)l, 16, 0, 0);
}

// ---- zero xp2 (halo must be 0; ws is poisoned each call) ----
__global__ void zero_xp2(u16* __restrict__ xp2, size_t n16) {
    size_t i = (size_t)blockIdx.x * blockDim.x + threadIdx.x;
    size_t stride = (size_t)gridDim.x * blockDim.x;
    uint4* p = (uint4*)xp2;
    uint4 z; z.x = z.y = z.z = z.w = 0u;
    for (; i < n16; i += stride) p[i] = z;
}

// ---- pack x -> xp2[n][h+6][w+6][c] bf16, c innermost ----
__global__ __launch_bounds__(256)
void pack_x(const float* __restrict__ x, u16* __restrict__ xp2) {
    int nh = blockIdx.x;
    int n = nh / HH, h = nh % HH;
    int lane = threadIdx.x & 63, wv = threadIdx.x >> 6;
    if (lane >= WW) return;
    const float* src = x + (size_t)n * (CC * HH * WW) + h * WW + lane;
    u16* dst = xp2 + (((size_t)n * HP + (h + 6)) * HP + (lane + 6)) * CC;
    for (int oct = wv; oct < 32; oct += 4) {
        s16x8 pk;
#pragma unroll
        for (int j = 0; j < 8; ++j)
            pk[j] = (short)f2bf(src[(size_t)(oct * 8 + j) * (HH * WW)]);
        *(s16x8*)(dst + oct * 8) = pk;
    }
}

// ---- pack w7 -> wt3[tap*8+chunk][c_out][32 cin] bf16 ----
__global__ __launch_bounds__(256)
void pack_w(const float* __restrict__ w7, u16* __restrict__ wt3) {
    int idx = blockIdx.x * 256 + threadIdx.x;    // 256*6400 total
    int c_out = idx / 6400;
    int k = idx - c_out * 6400;
    int cin = k / 25;
    int tap = k - cin * 25;
    int chunk = cin >> 5;
    int ci = cin & 31;
    wt3[(((size_t)(tap * 8 + chunk)) * CC + c_out) * 32 + ci] = f2bf(w7[idx]);
}

// ---- t1 (row max) + t9 (softmax over w of einsum) ----
__global__ __launch_bounds__(256)
void t169_kernel(const float* __restrict__ x, const float* __restrict__ w6,
                 float* __restrict__ t1, float* __restrict__ t9) {
    const int n = blockIdx.x / HH;
    const int h = blockIdx.x % HH;
    const int wave = threadIdx.x >> 6;
    const int lane = threadIdx.x & 63;
    const bool valid = lane < WW;
    const int wl = valid ? lane : (WW - 1);
    const float* xrow = x + ((size_t)(n * CC) * HH + h) * WW;
    float accw = 0.f;
    __shared__ float sbuf[4 * 64];
    for (int i = 0; i < 64; ++i) {
        int c = wave * 64 + i;
        float xv = xrow[(size_t)c * (HH * WW) + wl];
        float xm = valid ? xv : -INFINITY;
#pragma unroll
        for (int off = 32; off > 0; off >>= 1)
            xm = fmaxf(xm, __shfl_xor(xm, off));
        if (lane == 0) t1[(size_t)(n * CC + c) * HH + h] = xm;
        if (valid) accw += tanhf(fmaxf(xv, 0.f)) * w6[c];
    }
    sbuf[wave * 64 + lane] = accw;
    __syncthreads();
    if (wave == 0) {
        float s = sbuf[lane] + sbuf[64 + lane] + sbuf[128 + lane] + sbuf[192 + lane];
        float sm = valid ? s : -INFINITY;
        float mx = sm;
#pragma unroll
        for (int off = 32; off > 0; off >>= 1)
            mx = fmaxf(mx, __shfl_xor(mx, off));
        float e = valid ? expf(s - mx) : 0.f;
        float tot = e;
#pragma unroll
        for (int off = 32; off > 0; off >>= 1)
            tot += __shfl_xor(tot, off);
        if (valid) t9[((size_t)n * HH + h) * WW + lane] = e / tot;
    }
}

// ---- main: implicit GEMM, 256 couts x 256 flat-spatial per block, BK=32 ----
// 512 thr = 8 waves (2 cout-groups x 4 pos-groups), per-wave 128x64 output.
// 4 LDS buffers (32KB each: A 16KB + B 16KB), staged 3 tiles ahead via
// global_load_lds; counted s_waitcnt vmcnt(8) once per K-tile (T3+T4);
// setprio around MFMA clusters (T5). Waves 0-3 stage A (weights, contiguous
// 16KB/kn); waves 4-7 stage B (position gather). LDS rows are 64B -> every
// ds_read_b128 fragment is a contiguous 1KB wave read: bank-conflict-free.
__global__ __launch_bounds__(512, 2)
void conv_main(const char* __restrict__ xp2b, const char* __restrict__ wt3b,
               const float* __restrict__ x, const float* __restrict__ t1,
               const float* __restrict__ t9, float* __restrict__ out) {
    extern __shared__ __align__(16) char smem[];   // 4 * 32768 = 128 KiB
    const int tile = blockIdx.x;                    // positions [tile*256, +256)
    const int tid  = threadIdx.x;
    const int wid  = tid >> 6;
    const int lane = tid & 63;
    const int m = lane & 15;
    const int q = lane >> 4;
    const int wr = wid >> 2;          // cout half: rows [wr*128, +128)
    const int wc = wid & 3;           // pos quarter: cols [wc*64, +64)
    const bool isA = wid < 4;

    // B-gather source offsets (4 positions per thread), loop-invariant
    unsigned vb[4] = {0, 0, 0, 0};
    if (!isA) {
        const int wb = wid - 4;
#pragma unroll
        for (int i = 0; i < 4; ++i) {
            int p = tile * 256 + wb * 64 + i * 16 + (lane >> 2);
            int n = p / (HH * WW);
            int rem = p - n * (HH * WW);
            int hh = rem / WW;
            int ww = rem - hh * WW;
            vb[i] = ((((unsigned)n * HP + hh + 6) * HP) + ww + 6) * 512 + (lane & 3) * 16;
        }
    }

    // stage half a K-tile (2 gl_lds per thread). tt may exceed 199 (tail
    // dummies wrap to valid addresses; their buffers are never read).
    auto stage2 = [&](int tt, int half) {
        const int kn = (tt < 200) ? tt : (tt - 200);
        char* dst = smem + (size_t)(tt & 3) * 32768;
        if (isA) {
            const char* g = wt3b + (size_t)kn * 16384 + wid * 4096 + half * 2048 + lane * 16;
            char* d = dst + wid * 4096 + half * 2048 + lane * 16;
            gl_lds16(g, d);
            gl_lds16(g + 1024, d + 1024);
        } else {
            const int tp = kn >> 3, ch = kn & 7;
            const char* gb = xp2b +
                (ptrdiff_t)((tp / 5) * 3 - 6) * (HP * 512) +
                (ptrdiff_t)((tp % 5) * 3 - 6) * 512 + ch * 64;
            char* d = dst + 16384 + (wid - 4) * 4096 + half * 2048 + lane * 16;
            gl_lds16(gb + vb[half * 2],     d);
            gl_lds16(gb + vb[half * 2 + 1], d + 1024);
        }
    };

    f32x4 acc[8][4];
#pragma unroll
    for (int mi = 0; mi < 8; ++mi)
#pragma unroll
        for (int ni = 0; ni < 4; ++ni) {
            acc[mi][ni][0] = 0.f; acc[mi][ni][1] = 0.f;
            acc[mi][ni][2] = 0.f; acc[mi][ni][3] = 0.f;
        }

    // frag read offsets within a buffer (row = 64B)
    const int aoff = (wr * 128 + m) * 64 + q * 16;            // + mi*1024
    const int boff = 16384 + (wc * 64 + m) * 64 + q * 16;     // + ni*1024

    // prologue: stage tiles 0,1,2 (12 loads/wave); wait tile 0 landed
    stage2(0, 0); stage2(0, 1);
    stage2(1, 0); stage2(1, 1);
    stage2(2, 0); stage2(2, 1);
    asm volatile("s_waitcnt vmcnt(8)" ::: "memory");
    __builtin_amdgcn_s_barrier();

    for (int t = 0; t < 200; ++t) {
        const char* bp = smem + (size_t)(t & 3) * 32768;
        bf16x8 av[4], bv[4];

        // ---- phase 0: B frags + A frags 0-3, stage half 0 of tile t+3 ----
        stage2(t + 3, 0);
#pragma unroll
        for (int ni = 0; ni < 4; ++ni)
            bv[ni] = *(const bf16x8*)(const void*)(bp + boff + ni * 1024);
#pragma unroll
        for (int mi = 0; mi < 4; ++mi)
            av[mi] = *(const bf16x8*)(const void*)(bp + aoff + mi * 1024);
        __builtin_amdgcn_s_setprio(1);
#pragma unroll
        for (int mi = 0; mi < 4; ++mi)
#pragma unroll
            for (int ni = 0; ni < 4; ++ni)
                acc[mi][ni] = __builtin_amdgcn_mfma_f32_16x16x32_bf16(
                    av[mi], bv[ni], acc[mi][ni], 0, 0, 0);
        __builtin_amdgcn_s_setprio(0);
        __builtin_amdgcn_s_barrier();

        // ---- phase 1: A frags 4-7 (bv held in regs), stage half 1 ----
        stage2(t + 3, 1);
#pragma unroll
        for (int mi = 0; mi < 4; ++mi)
            av[mi] = *(const bf16x8*)(const void*)(bp + aoff + 4096 + mi * 1024);
        __builtin_amdgcn_s_setprio(1);
#pragma unroll
        for (int mi = 0; mi < 4; ++mi)
#pragma unroll
            for (int ni = 0; ni < 4; ++ni)
                acc[mi + 4][ni] = __builtin_amdgcn_mfma_f32_16x16x32_bf16(
                    av[mi], bv[ni], acc[mi + 4][ni], 0, 0, 0);
        __builtin_amdgcn_s_setprio(0);
        // counted wait: tiles t+2, t+3 (8 gl_lds/wave) stay in flight;
        // guarantees tile t+1 fully landed before the barrier releases.
        asm volatile("s_waitcnt vmcnt(8)" ::: "memory");
        __builtin_amdgcn_s_barrier();
    }

    // epilogue: out = t1 - (t9 * roll(x,2,h) + x * t7)
#pragma unroll
    for (int ni = 0; ni < 4; ++ni) {
        const int p = tile * 256 + wc * 64 + ni * 16 + m;
        const int n = p / (HH * WW);
        const int rem = p - n * (HH * WW);
        const int h = rem / WW;
        const int w = rem - h * WW;
        const float t9v = t9[((size_t)n * HH + h) * WW + w];
        const int hprev = (h >= 2) ? (h - 2) : (h + HH - 2);
#pragma unroll
        for (int mi = 0; mi < 8; ++mi) {
            const int c = wr * 128 + mi * 16 + q * 4;
#pragma unroll
            for (int r = 0; r < 4; ++r) {
                const size_t rowi = (size_t)(n * CC + c + r) * HH;
                const float t1v = t1[rowi + h];
                const float xv = x[(rowi + h) * WW + w];
                const float xr = x[(rowi + hprev) * WW + w];
                out[(rowi + h) * WW + w] = t1v - (t9v * xr + xv * acc[mi][ni][r]);
            }
        }
    }
}

extern "C" void kernel_launch(void* const* d_in, const int* in_sizes, int n_in,
                              void* d_out, int out_size, void* d_ws, size_t ws_size,
                              hipStream_t stream) {
    const float* x  = (const float*)d_in[0];
    const float* w6 = (const float*)d_in[1];
    const float* w7 = (const float*)d_in[2];
    float* out = (float*)d_out;
    char* ws = (char*)d_ws;
    u16*   xp2 = (u16*)(ws + XP2_OFF);
    u16*   wt3 = (u16*)(ws + WT3_OFF);
    float* t1  = (float*)(ws + T1_OFF);
    float* t9  = (float*)(ws + T9_OFF);

    static bool lds_cfg_done = false;
    if (!lds_cfg_done) {
        (void)hipFuncSetAttribute((const void*)conv_main,
                                  hipFuncAttributeMaxDynamicSharedMemorySize,
                                  131072);
        lds_cfg_done = true;
    }

    zero_xp2<<<dim3(2048), dim3(256), 0, stream>>>(xp2, XP2_BYTES / 16);
    pack_x<<<dim3(NN * HH), dim3(256), 0, stream>>>(x, xp2);
    pack_w<<<dim3(6400), dim3(256), 0, stream>>>(w7, wt3);
    t169_kernel<<<dim3(NN * HH), dim3(256), 0, stream>>>(x, w6, t1, t9);
    conv_main<<<dim3(392), dim3(512), 131072, stream>>>((const char*)xp2, (const char*)wt3,
                                                        x, t1, t9, out);
}